// Round 3
// baseline (168.249 us; speedup 1.0000x reference)
//
#include <hip/hip_runtime.h>
#include <math.h>

#define BATCH    128
#define N_ATOMS  4096
#define NB       4095
#define NA       4094
#define NT       4093
#define FSTRIDE  184185                // floats per sample
#define ROWS     20465                 // MAX_LEN rows of 9 floats
#define CROWS    12288                 // coord elements (3*N_ATOMS)
#define BROWS    12285                 // bond elements  (3*NB)
#define AROWS    16376                 // angle elements (4*NA)
#define EPSV     1e-8f
#define THREADS  1024
#define WAVES    16
#define TPR      120                   // rows per tile (2 rows per lane)

// ---- two-pass geometry ----
#define HROWS    10232                 // rows owned by h=0 block; h=1 owns 10233
#define K1TILES  86                    // ceil(10233 / 120)
// workspace layout: per-sample slot, byte offsets (all 4-aligned)
#define WS_BOFF  49152                 // [0,49152)       coords f32[12288]
#define WS_AOFF  73724                 // [49152,73724)   bonds  u16[12286] (1 pad)
#define WS_TOFF  106476                // [73724,106476)  angles u16[16376]
#define WS_SLOT  147456                // [106476,147408) tors u16[20466] (1 pad); slot padded
#define WS_NEED  ((size_t)WS_SLOT * BATCH)   // 18,874,368 B

// 4-byte-aligned float4: row R's cols 5..8 live at float offset 9R+5 (mod-4 varies).
typedef float float4a __attribute__((ext_vector_type(4), aligned(4)));

// v14: two-pass through d_ws.
// Evidence (v12/v13 A/Bs): v11's twin blocks do NOT get L2 dedup -- Phase A is
// HBM-bound at ~188 MB (2x the 94.3 MB footprint). K1 gives each block a
// DISJOINT half-sample row range (single-fetch by construction, no scheduler
// assumptions), reuses v11's barrier-free gather-extraction, and bulk-writes
// compact columns (18.9 MB) coalesced. K2 is v11's twin split reading compact
// columns (25 MB coalesced) with Phase B verbatim -> identical numerics.

// ======================= K1: stream + compact =======================
__global__ __launch_bounds__(THREADS, 1) void
compact_k1(const float* __restrict__ F, unsigned char* __restrict__ ws)
{
    __shared__ __align__(16) float          lc[HROWS];        // 40928 B
    __shared__ __align__(16) unsigned short lb[HROWS + 2];    // 20468 B
    __shared__ __align__(16) unsigned short la[HROWS];        // 20464 B
    __shared__ __align__(16) unsigned short lt[HROWS + 2];    // 20468 B  (total 102,328)

    const int b      = blockIdx.x;
    const int s      = b >> 1;
    const int h      = b & 1;
    const int tid    = threadIdx.x;
    const int w      = tid >> 6;
    const int l      = tid & 63;
    const int base   = h * HROWS;
    const int rcount = HROWS + h;                  // 10232 / 10233
    const int limC   = max(0, min(CROWS - base, rcount));   // h0:10232 h1:2056
    const int limB   = max(0, min(BROWS - base, rcount));   // h0:10232 h1:2053
    const int limA   = max(0, min(AROWS - base, rcount));   // h0:10232 h1:6144
    const int limT   = rcount;                              // h0:10232 h1:10233
    const float* Fb  = F + (size_t)s * FSTRIDE;

    // v11-style barrier-free gather: lane l owns local rows 120t+2l, +2l+1.
    for (int t = w; t < K1TILES; t += WAVES) {
        const int r0 = TPR * t + 2 * l;            // even local row
        const int r1 = r0 + 1;
        float4a v0, v1;
        if (r0 < rcount) v0 = *(const float4a*)(Fb + (size_t)9 * (base + r0) + 5);
        if (r1 < rcount) v1 = *(const float4a*)(Fb + (size_t)9 * (base + r1) + 5);

        if (r1 < limC) {                           // coords
            float2 c2; c2.x = v0.x; c2.y = v1.x;
            *(float2*)(lc + r0) = c2;
        } else if (r0 < limC) {
            lc[r0] = v0.x;
        }
        if (r1 < limB) {                           // bonds
            unsigned pk = (unsigned)(unsigned short)(int)v0.y
                        | ((unsigned)(unsigned short)(int)v1.y << 16);
            *(unsigned*)(lb + r0) = pk;
        } else if (r0 < limB) {
            lb[r0] = (unsigned short)(int)v0.y;
        }
        if (r1 < limA) {                           // angles
            unsigned pk = (unsigned)(unsigned short)(int)v0.z
                        | ((unsigned)(unsigned short)(int)v1.z << 16);
            *(unsigned*)(la + r0) = pk;
        } else if (r0 < limA) {
            la[r0] = (unsigned short)(int)v0.z;
        }
        if (r1 < limT) {                           // torsions
            unsigned pk = (unsigned)(unsigned short)(int)v0.w
                        | ((unsigned)(unsigned short)(int)v1.w << 16);
            *(unsigned*)(lt + r0) = pk;
        } else if (r0 < limT) {
            lt[r0] = (unsigned short)(int)v0.w;
        }
    }
    __syncthreads();

    // Bulk coalesced LDS -> global (u32 granularity; base is even so all
    // region offsets are 4-aligned; odd u16 counts round up into the pads).
    unsigned char* wsS = ws + (size_t)s * WS_SLOT;
    {
        const unsigned* src = (const unsigned*)lc;
        unsigned*       dst = (unsigned*)wsS + base;
        for (int i = tid; i < limC; i += THREADS) dst[i] = src[i];
    }
    {
        const unsigned* src = (const unsigned*)lb;
        unsigned*       dst = (unsigned*)(wsS + WS_BOFF) + (base >> 1);
        const int n = (limB * 2 + 3) >> 2;
        for (int i = tid; i < n; i += THREADS) dst[i] = src[i];
    }
    {
        const unsigned* src = (const unsigned*)la;
        unsigned*       dst = (unsigned*)(wsS + WS_AOFF) + (base >> 1);
        const int n = (limA * 2 + 3) >> 2;
        for (int i = tid; i < n; i += THREADS) dst[i] = src[i];
    }
    {
        const unsigned* src = (const unsigned*)lt;
        unsigned*       dst = (unsigned*)(wsS + WS_TOFF) + (base >> 1);
        const int n = (limT * 2 + 3) >> 2;
        for (int i = tid; i < n; i += THREADS) dst[i] = src[i];
    }
}

// ======================= K2: compute from compact =======================
__global__ __launch_bounds__(THREADS, 1) void
energy_k2(const unsigned char* __restrict__ ws,
          const float* __restrict__ bond_type,
          const float* __restrict__ angle_type,
          const float* __restrict__ tor_type,
          const int*   __restrict__ multiplicity,
          const float* __restrict__ opt_pars,
          float*       __restrict__ out)
{
    __shared__ float scc[CROWS];                  // 48 KB
    __shared__ union IdxU {
        struct { unsigned short bB[BROWS + 1];    // p1: bonds + angles (57.3 KB)
                 unsigned short bA[AROWS]; } q;
        unsigned short bT[ROWS + 1];              // p0: torsions (40.9 KB)
    } u;
    __shared__ float sbt[30], sat[26], stt[50], smu[25];
    __shared__ float sred[WAVES * 2];

    const int b   = blockIdx.x;
    const int s   = b & 127;
    const int p   = b >> 7;                        // 0: torsions  1: bonds+angles
    const int tid = threadIdx.x;
    const int w   = tid >> 6;
    const int l   = tid & 63;

    if (tid < 30)                      sbt[tid]       = bond_type[tid];
    else if (tid >= 32 && tid < 58)    sat[tid - 32]  = angle_type[tid - 32];
    else if (tid >= 64 && tid < 114)   stt[tid - 64]  = tor_type[tid - 64];
    else if (tid >= 128 && tid < 153)  smu[tid - 128] = (float)multiplicity[tid - 128];

    const unsigned char* wsS = ws + (size_t)s * WS_SLOT;
    {   // coords: 12288 u32
        const unsigned* src = (const unsigned*)wsS;
        unsigned*       dst = (unsigned*)scc;
        for (int i = tid; i < 12288; i += THREADS) dst[i] = src[i];
    }
    if (p) {
        const unsigned* srcB = (const unsigned*)(wsS + WS_BOFF);
        unsigned*       dstB = (unsigned*)u.q.bB;
        for (int i = tid; i < 6143; i += THREADS) dstB[i] = srcB[i];   // 24572 B
        const unsigned* srcA = (const unsigned*)(wsS + WS_AOFF);
        unsigned*       dstA = (unsigned*)u.q.bA;
        for (int i = tid; i < 8188; i += THREADS) dstA[i] = srcA[i];   // 32752 B
    } else {
        const unsigned* srcT = (const unsigned*)(wsS + WS_TOFF);
        unsigned*       dstT = (unsigned*)u.bT;
        for (int i = tid; i < 10233; i += THREADS) dstT[i] = srcT[i];  // 40932 B
    }
    __syncthreads();

    // ---- Phase B: verbatim v11 (identical striding -> identical numerics) ----
    float eA = 0.f, eB = 0.f;          // p0: eA=tor | p1: eA=bond, eB=angle
    if (p) {
        for (int i = tid; i < NB; i += THREADS) {
            const int a0 = u.q.bB[3 * i + 0];
            const int a1 = u.q.bB[3 * i + 1];
            const int bt = u.q.bB[3 * i + 2];
            const float dx = scc[3 * a0 + 0] - scc[3 * a1 + 0];
            const float dy = scc[3 * a0 + 1] - scc[3 * a1 + 1];
            const float dz = scc[3 * a0 + 2] - scc[3 * a1 + 2];
            const float r  = sqrtf(dx * dx + dy * dy + dz * dz + EPSV);
            const float t0 = r - sbt[bt * 2 + 1];
            eA += sbt[bt * 2 + 0] * t0 * t0;
        }
        for (int i = tid; i < NA; i += THREADS) {
            const int a0 = u.q.bA[4 * i + 0];
            const int a1 = u.q.bA[4 * i + 1];
            const int a2 = u.q.bA[4 * i + 2];
            const int at = u.q.bA[4 * i + 3];
            const float v1x = scc[3 * a0 + 0] - scc[3 * a1 + 0];
            const float v1y = scc[3 * a0 + 1] - scc[3 * a1 + 1];
            const float v1z = scc[3 * a0 + 2] - scc[3 * a1 + 2];
            const float v2x = scc[3 * a2 + 0] - scc[3 * a1 + 0];
            const float v2y = scc[3 * a2 + 1] - scc[3 * a1 + 1];
            const float v2z = scc[3 * a2 + 2] - scc[3 * a1 + 2];
            const float d12 = v1x * v2x + v1y * v2y + v1z * v2z;
            const float n1  = sqrtf(v1x * v1x + v1y * v1y + v1z * v1z + EPSV);
            const float n2  = sqrtf(v2x * v2x + v2y * v2y + v2z * v2z + EPSV);
            float cosang = d12 / (n1 * n2);
            cosang = fminf(fmaxf(cosang, -1.0f + 1e-6f), 1.0f - 1e-6f);
            const float t0 = acosf(cosang) - sat[at * 2 + 1];
            eB += sat[at * 2 + 0] * t0 * t0;
        }
    } else {
        for (int i = tid; i < NT; i += THREADS) {
            const int ai = u.bT[5 * i + 0];
            const int aj = u.bT[5 * i + 1];
            const int ak = u.bT[5 * i + 2];
            const int al = u.bT[5 * i + 3];
            const int tt = u.bT[5 * i + 4];
            const float b1x = scc[3*aj+0] - scc[3*ai+0];
            const float b1y = scc[3*aj+1] - scc[3*ai+1];
            const float b1z = scc[3*aj+2] - scc[3*ai+2];
            const float b2x = scc[3*ak+0] - scc[3*aj+0];
            const float b2y = scc[3*ak+1] - scc[3*aj+1];
            const float b2z = scc[3*ak+2] - scc[3*aj+2];
            const float b3x = scc[3*al+0] - scc[3*ak+0];
            const float b3y = scc[3*al+1] - scc[3*ak+1];
            const float b3z = scc[3*al+2] - scc[3*ak+2];
            const float n1x = b1y*b2z - b1z*b2y;
            const float n1y = b1z*b2x - b1x*b2z;
            const float n1z = b1x*b2y - b1y*b2x;
            const float n2x = b2y*b3z - b2z*b3y;
            const float n2y = b2z*b3x - b2x*b3z;
            const float n2z = b2x*b3y - b2y*b3x;
            const float inv = 1.0f / sqrtf(b2x*b2x + b2y*b2y + b2z*b2z + EPSV);
            const float bnx = b2x * inv, bny = b2y * inv, bnz = b2z * inv;
            const float m1x = n1y*bnz - n1z*bny;
            const float m1y = n1z*bnx - n1x*bnz;
            const float m1z = n1x*bny - n1y*bnx;
            const float phi = atan2f(m1x*n2x + m1y*n2y + m1z*n2z,
                                     n1x*n2x + n1y*n2y + n1z*n2z);
            eA += stt[tt * 2 + 0] * (1.0f + cosf(smu[tt] * phi - stt[tt * 2 + 1]));
        }
    }

    for (int off = 32; off > 0; off >>= 1) {
        eA += __shfl_down(eA, off);
        eB += __shfl_down(eB, off);
    }
    if (l == 0) {
        sred[w * 2 + 0] = eA;
        sred[w * 2 + 1] = eB;
    }
    __syncthreads();
    if (tid == 0) {
        float rA = 0.f, rB = 0.f;
        for (int i = 0; i < WAVES; ++i) { rA += sred[i * 2]; rB += sred[i * 2 + 1]; }
        if (p) {
            out[s * 3 + 0] = opt_pars[0] * rA;   // bonds
            out[s * 3 + 1] = opt_pars[1] * rB;   // angles
        } else {
            out[s * 3 + 2] = opt_pars[2] * rA;   // torsions
        }
    }
}

// ======================= Fallback: v11 (best single-kernel) =======================
__global__ __launch_bounds__(THREADS, 1) void
local_energy_v11(const float* __restrict__ F,
                 const float* __restrict__ bond_type,
                 const float* __restrict__ angle_type,
                 const float* __restrict__ tor_type,
                 const int*   __restrict__ multiplicity,
                 const float* __restrict__ opt_pars,
                 float*       __restrict__ out)
{
    __shared__ float          scc[CROWS];
    __shared__ unsigned short sbB[BROWS + 1];
    __shared__ unsigned short sbA[AROWS];
    __shared__ unsigned short sbT[ROWS + 1];
    __shared__ float sbt[30], sat[26], stt[50], smu[25];
    __shared__ float sred[WAVES * 2];

    const int b   = blockIdx.x;
    const int x   = b & 7;
    const int g   = b >> 3;
    const int s   = (g & 15) * 8 + x;
    const int p   = g >> 4;
    const int tid = threadIdx.x;
    const int w   = tid >> 6;
    const int l   = tid & 63;
    const size_t sbase = (size_t)s * FSTRIDE;

    if (tid < 30)                      sbt[tid]       = bond_type[tid];
    else if (tid >= 32 && tid < 58)    sat[tid - 32]  = angle_type[tid - 32];
    else if (tid >= 64 && tid < 114)   stt[tid - 64]  = tor_type[tid - 64];
    else if (tid >= 128 && tid < 153)  smu[tid - 128] = (float)multiplicity[tid - 128];

    const int tmax = p ? 137 : 171;
    for (int t = w; t < tmax; t += WAVES) {
        const int R0 = TPR * t + 2 * l;
        const int R1 = R0 + 1;
        float4a v0, v1;
        const bool ok0 = (R0 < ROWS);
        const bool ok1 = (R1 < ROWS);
        if (ok0) v0 = *(const float4a*)(F + sbase + (size_t)9 * R0 + 5);
        if (ok1) v1 = *(const float4a*)(F + sbase + (size_t)9 * R1 + 5);
        if (R1 < CROWS) {
            float2 c2; c2.x = v0.x; c2.y = v1.x;
            *(float2*)(scc + R0) = c2;
        }
        if (p) {
            if (R1 < BROWS) {
                unsigned pk = (unsigned)(unsigned short)(int)v0.y
                            | ((unsigned)(unsigned short)(int)v1.y << 16);
                *(unsigned*)(sbB + R0) = pk;
            } else if (R0 < BROWS) {
                sbB[R0] = (unsigned short)(int)v0.y;
            }
            if (R1 < AROWS) {
                unsigned pk = (unsigned)(unsigned short)(int)v0.z
                            | ((unsigned)(unsigned short)(int)v1.z << 16);
                *(unsigned*)(sbA + R0) = pk;
            }
        } else {
            if (ok1) {
                unsigned pk = (unsigned)(unsigned short)(int)v0.w
                            | ((unsigned)(unsigned short)(int)v1.w << 16);
                *(unsigned*)(sbT + R0) = pk;
            } else if (ok0) {
                sbT[R0] = (unsigned short)(int)v0.w;
            }
        }
    }
    __syncthreads();

    float eA = 0.f, eB = 0.f;
    if (p) {
        for (int i = tid; i < NB; i += THREADS) {
            const int a0 = sbB[3 * i + 0];
            const int a1 = sbB[3 * i + 1];
            const int bt = sbB[3 * i + 2];
            const float dx = scc[3 * a0 + 0] - scc[3 * a1 + 0];
            const float dy = scc[3 * a0 + 1] - scc[3 * a1 + 1];
            const float dz = scc[3 * a0 + 2] - scc[3 * a1 + 2];
            const float r  = sqrtf(dx * dx + dy * dy + dz * dz + EPSV);
            const float t0 = r - sbt[bt * 2 + 1];
            eA += sbt[bt * 2 + 0] * t0 * t0;
        }
        for (int i = tid; i < NA; i += THREADS) {
            const int a0 = sbA[4 * i + 0];
            const int a1 = sbA[4 * i + 1];
            const int a2 = sbA[4 * i + 2];
            const int at = sbA[4 * i + 3];
            const float v1x = scc[3 * a0 + 0] - scc[3 * a1 + 0];
            const float v1y = scc[3 * a0 + 1] - scc[3 * a1 + 1];
            const float v1z = scc[3 * a0 + 2] - scc[3 * a1 + 2];
            const float v2x = scc[3 * a2 + 0] - scc[3 * a1 + 0];
            const float v2y = scc[3 * a2 + 1] - scc[3 * a1 + 1];
            const float v2z = scc[3 * a2 + 2] - scc[3 * a1 + 2];
            const float d12 = v1x * v2x + v1y * v2y + v1z * v2z;
            const float n1  = sqrtf(v1x * v1x + v1y * v1y + v1z * v1z + EPSV);
            const float n2  = sqrtf(v2x * v2x + v2y * v2y + v2z * v2z + EPSV);
            float cosang = d12 / (n1 * n2);
            cosang = fminf(fmaxf(cosang, -1.0f + 1e-6f), 1.0f - 1e-6f);
            const float t0 = acosf(cosang) - sat[at * 2 + 1];
            eB += sat[at * 2 + 0] * t0 * t0;
        }
    } else {
        for (int i = tid; i < NT; i += THREADS) {
            const int ai = sbT[5 * i + 0];
            const int aj = sbT[5 * i + 1];
            const int ak = sbT[5 * i + 2];
            const int al = sbT[5 * i + 3];
            const int tt = sbT[5 * i + 4];
            const float b1x = scc[3*aj+0] - scc[3*ai+0];
            const float b1y = scc[3*aj+1] - scc[3*ai+1];
            const float b1z = scc[3*aj+2] - scc[3*ai+2];
            const float b2x = scc[3*ak+0] - scc[3*aj+0];
            const float b2y = scc[3*ak+1] - scc[3*aj+1];
            const float b2z = scc[3*ak+2] - scc[3*aj+2];
            const float b3x = scc[3*al+0] - scc[3*ak+0];
            const float b3y = scc[3*al+1] - scc[3*ak+1];
            const float b3z = scc[3*al+2] - scc[3*ak+2];
            const float n1x = b1y*b2z - b1z*b2y;
            const float n1y = b1z*b2x - b1x*b2z;
            const float n1z = b1x*b2y - b1y*b2x;
            const float n2x = b2y*b3z - b2z*b3y;
            const float n2y = b2z*b3x - b2x*b3z;
            const float n2z = b2x*b3y - b2y*b3x;
            const float inv = 1.0f / sqrtf(b2x*b2x + b2y*b2y + b2z*b2z + EPSV);
            const float bnx = b2x * inv, bny = b2y * inv, bnz = b2z * inv;
            const float m1x = n1y*bnz - n1z*bny;
            const float m1y = n1z*bnx - n1x*bnz;
            const float m1z = n1x*bny - n1y*bnx;
            const float phi = atan2f(m1x*n2x + m1y*n2y + m1z*n2z,
                                     n1x*n2x + n1y*n2y + n1z*n2z);
            eA += stt[tt * 2 + 0] * (1.0f + cosf(smu[tt] * phi - stt[tt * 2 + 1]));
        }
    }

    for (int off = 32; off > 0; off >>= 1) {
        eA += __shfl_down(eA, off);
        eB += __shfl_down(eB, off);
    }
    if (l == 0) {
        sred[w * 2 + 0] = eA;
        sred[w * 2 + 1] = eB;
    }
    __syncthreads();
    if (tid == 0) {
        float rA = 0.f, rB = 0.f;
        for (int i = 0; i < WAVES; ++i) { rA += sred[i * 2]; rB += sred[i * 2 + 1]; }
        if (p) {
            out[s * 3 + 0] = opt_pars[0] * rA;
            out[s * 3 + 1] = opt_pars[1] * rB;
        } else {
            out[s * 3 + 2] = opt_pars[2] * rA;
        }
    }
}

extern "C" void kernel_launch(void* const* d_in, const int* in_sizes, int n_in,
                              void* d_out, int out_size, void* d_ws, size_t ws_size,
                              hipStream_t stream) {
    const float* F            = (const float*)d_in[0];
    // d_in[1] = lengths (constant, unused)
    const float* bond_type    = (const float*)d_in[2];
    const float* angle_type   = (const float*)d_in[3];
    const float* tor_type     = (const float*)d_in[4];
    const int*   multiplicity = (const int*)  d_in[5];
    const float* opt_pars     = (const float*)d_in[6];
    float* out = (float*)d_out;

    if (d_ws != nullptr && ws_size >= WS_NEED) {
        // Two-pass: K1 compacts (disjoint row halves -> single-fetch of F
        // guaranteed), K2 computes. Stream-ordered -> K2 sees K1's writes.
        compact_k1<<<dim3(BATCH * 2), dim3(THREADS), 0, stream>>>(
            F, (unsigned char*)d_ws);
        energy_k2<<<dim3(BATCH * 2), dim3(THREADS), 0, stream>>>(
            (const unsigned char*)d_ws, bond_type, angle_type, tor_type,
            multiplicity, opt_pars, out);
    } else {
        // Fallback: best single-kernel version (v11).
        local_energy_v11<<<dim3(BATCH * 2), dim3(THREADS), 0, stream>>>(
            F, bond_type, angle_type, tor_type, multiplicity, opt_pars, out);
    }
}

// Round 4
// 163.359 us; speedup vs baseline: 1.0299x; 1.0299x over previous
//
#include <hip/hip_runtime.h>
#include <math.h>

#define BATCH    128
#define N_ATOMS  4096
#define NB       4095
#define NA       4094
#define NT       4093
#define FSTRIDE  184185                // floats per sample (= 9 * 20465)
#define ROWS     20465
#define CROWS    12288                 // coord elements (3*N_ATOMS)
#define BROWS    12285                 // bond elements  (3*NB)
#define AROWS    16376                 // angle elements (4*NA)
#define TROWS    20465                 // torsion elements (5*NT)
#define EPSV     1e-8f
#define THREADS  1024
#define WAVES    16

// chunks of 4 floats: 46046 full chunks + 1 single-float tail (f = 184184)
#define NCHUNK_FULL 46046

// ---- flat LDS layout (byte offsets) ----
#define OFF_SCC  0                     // f32[12288]          49152 B
#define OFF_B    49152                 // u16[12288 res]      24576 B
#define OFF_A    73728                 // u16[16376]          32752 B
#define OFF_T    106480                // u16[20466 res]      40932 B
#define OFF_SBT  147412                // f32[30]
#define OFF_SAT  147532                // f32[26]
#define OFF_STT  147636                // f32[50]
#define OFF_SMU  147836                // f32[25]
#define OFF_SRED 147936                // f32[48]
#define OFF_D4   148128                // dummy f32 sink
#define OFF_D2   148132                // dummy u16 sink
#define LDS_SZ   148160

// 4-byte-aligned float4 (sample base is only 4B-aligned; CDNA multi-dword
// loads need dword alignment only -- v11 relied on this too).
typedef float float4a __attribute__((ext_vector_type(4), aligned(4)));

// v15: contiguous-load + arithmetic scatter-extract, one block per sample.
// Evidence (v11..v14 fits): the kernel was TA-bound on the 72B-stride gather
// (~256 cyc/wave-instr, 64 distinct lines/instr), NOT HBM-bound. v15 loads
// contiguous 1KiB/wave-instr (TA-coalesced) and scatters cols 5..8 directly
// to compact LDS. Key fact: for a float4 with c0 = f0 mod 9, a wanted column
// (5..8) NEVER wraps the row boundary -> (col,row) = (c0+e, r0) with no
// per-element divmod. 4 unconditional dummy-redirected LDS writes per chunk.
// Single block per sample -> F fetched exactly once (94.3 MB), no dedup
// assumptions, no second pass, no staging barriers.

__device__ __forceinline__ float sel4f(const float4a v, const int e) {
    float r = v.w;
    r = (e == 0) ? v.x : r;
    r = (e == 1) ? v.y : r;
    r = (e == 2) ? v.z : r;
    return r;                          // e outside [0,3] -> garbage (masked)
}

__device__ __forceinline__ void extract_chunk(char* __restrict__ lds,
                                              const float4a v,
                                              const int r0, const int c0) {
    // coord (col 5): valid c0 in {2..5}
    {
        const float cv = sel4f(v, 5 - c0);
        const bool  ok = ((unsigned)(5 - c0) < 4u) && (r0 < CROWS);
        const int   ad = ok ? (OFF_SCC + (r0 << 2)) : OFF_D4;
        *(float*)(lds + ad) = cv;
    }
    // bond (col 6): valid c0 in {3..6}
    {
        const int  iv = (int)sel4f(v, 6 - c0);
        const bool ok = ((unsigned)(6 - c0) < 4u) && (r0 < BROWS);
        const int  ad = ok ? (OFF_B + (r0 << 1)) : OFF_D2;
        *(unsigned short*)(lds + ad) = (unsigned short)iv;
    }
    // angle (col 7): valid c0 in {4..7}
    {
        const int  iv = (int)sel4f(v, 7 - c0);
        const bool ok = ((unsigned)(7 - c0) < 4u) && (r0 < AROWS);
        const int  ad = ok ? (OFF_A + (r0 << 1)) : OFF_D2;
        *(unsigned short*)(lds + ad) = (unsigned short)iv;
    }
    // torsion (col 8): valid c0 in {5..8}; r0 <= 20463 for full chunks -> no r check
    {
        const int  iv = (int)sel4f(v, 8 - c0);
        const bool ok = ((unsigned)(8 - c0) < 4u);
        const int  ad = ok ? (OFF_T + (r0 << 1)) : OFF_D2;
        *(unsigned short*)(lds + ad) = (unsigned short)iv;
    }
}

__global__ __launch_bounds__(THREADS, 1) void
local_energy_v15(const float* __restrict__ F,
                 const float* __restrict__ bond_type,   // 15 x 2
                 const float* __restrict__ angle_type,  // 13 x 2
                 const float* __restrict__ tor_type,    // 25 x 2
                 const int*   __restrict__ multiplicity,// 25
                 const float* __restrict__ opt_pars,    // 47
                 float*       __restrict__ out)         // B x 3
{
    __shared__ __align__(16) char LDSM[LDS_SZ];
    char* lds = LDSM;

    const int s   = blockIdx.x;        // sample 0..127
    const int tid = threadIdx.x;
    const int w   = tid >> 6;
    const int l   = tid & 63;
    const float* Fb = F + (size_t)s * FSTRIDE;

    float* sbt = (float*)(lds + OFF_SBT);
    float* sat = (float*)(lds + OFF_SAT);
    float* stt = (float*)(lds + OFF_STT);
    float* smu = (float*)(lds + OFF_SMU);
    float* srd = (float*)(lds + OFF_SRED);

    if (tid < 30)                      sbt[tid]       = bond_type[tid];
    else if (tid >= 32 && tid < 58)    sat[tid - 32]  = angle_type[tid - 32];
    else if (tid >= 64 && tid < 114)   stt[tid - 64]  = tor_type[tid - 64];
    else if (tid >= 128 && tid < 153)  smu[tid - 128] = (float)multiplicity[tid - 128];

    // ======== Phase A: contiguous stream + scatter extract ========
    // Thread handles chunks tid + 1024*j, j = 0..44. Pairs (j, j+1) for
    // j <= 43 are ALL full chunks (max ci = 45055 < 46046) -> unguarded hot
    // loop with 2 loads in flight (32 KB/CU) to cover HBM latency.
    int r0 = (4 * tid) / 9;
    int c0 = 4 * tid - 9 * r0;

    for (int j = 0; j < 44; j += 2) {
        const int ci0 = tid + (j << 10);
        const float4a v0 = *(const float4a*)(Fb + 4 * ci0);
        const float4a v1 = *(const float4a*)(Fb + 4 * ci0 + 4096);
        extract_chunk(lds, v0, r0, c0);
        // advance by 4096 floats: +455 rows, +1 col (4096 = 9*455 + 1)
        { c0 += 1; r0 += 455; if (c0 == 9) { c0 = 0; r0 += 1; } }
        extract_chunk(lds, v1, r0, c0);
        { c0 += 1; r0 += 455; if (c0 == 9) { c0 = 0; r0 += 1; } }
    }
    // j = 44 solo: ci in [45056, 46079]
    {
        const int ci = tid + 45056;
        if (ci < NCHUNK_FULL) {
            const float4a v = *(const float4a*)(Fb + 4 * ci);
            extract_chunk(lds, v, r0, c0);
        } else if (ci == NCHUNK_FULL) {
            // final float f = 184184: row 20464, col 8 -> last torsion slot
            const float x = Fb[FSTRIDE - 1];
            *(unsigned short*)(lds + OFF_T + (20464 << 1)) = (unsigned short)(int)x;
        }
    }
    __syncthreads();

    const float*          scc = (const float*)(lds + OFF_SCC);
    const unsigned short* pB  = (const unsigned short*)(lds + OFF_B);
    const unsigned short* pA  = (const unsigned short*)(lds + OFF_A);
    const unsigned short* pT  = (const unsigned short*)(lds + OFF_T);

    // ======== Phase B: all three terms (striding identical to v12: passed) ====
    float eB = 0.f, eG = 0.f, eT = 0.f;
    for (int i = tid; i < NB; i += THREADS) {
        const int a0 = pB[3 * i + 0];
        const int a1 = pB[3 * i + 1];
        const int bt = pB[3 * i + 2];
        const float dx = scc[3 * a0 + 0] - scc[3 * a1 + 0];
        const float dy = scc[3 * a0 + 1] - scc[3 * a1 + 1];
        const float dz = scc[3 * a0 + 2] - scc[3 * a1 + 2];
        const float r  = sqrtf(dx * dx + dy * dy + dz * dz + EPSV);
        const float t0 = r - sbt[bt * 2 + 1];
        eB += sbt[bt * 2 + 0] * t0 * t0;
    }
    for (int i = tid; i < NA; i += THREADS) {
        const int a0 = pA[4 * i + 0];
        const int a1 = pA[4 * i + 1];
        const int a2 = pA[4 * i + 2];
        const int at = pA[4 * i + 3];
        const float v1x = scc[3 * a0 + 0] - scc[3 * a1 + 0];
        const float v1y = scc[3 * a0 + 1] - scc[3 * a1 + 1];
        const float v1z = scc[3 * a0 + 2] - scc[3 * a1 + 2];
        const float v2x = scc[3 * a2 + 0] - scc[3 * a1 + 0];
        const float v2y = scc[3 * a2 + 1] - scc[3 * a1 + 1];
        const float v2z = scc[3 * a2 + 2] - scc[3 * a1 + 2];
        const float d12 = v1x * v2x + v1y * v2y + v1z * v2z;
        const float n1  = sqrtf(v1x * v1x + v1y * v1y + v1z * v1z + EPSV);
        const float n2  = sqrtf(v2x * v2x + v2y * v2y + v2z * v2z + EPSV);
        float cosang = d12 / (n1 * n2);
        cosang = fminf(fmaxf(cosang, -1.0f + 1e-6f), 1.0f - 1e-6f);
        const float t0 = acosf(cosang) - sat[at * 2 + 1];
        eG += sat[at * 2 + 0] * t0 * t0;
    }
    for (int i = tid; i < NT; i += THREADS) {
        const int ai = pT[5 * i + 0];
        const int aj = pT[5 * i + 1];
        const int ak = pT[5 * i + 2];
        const int al = pT[5 * i + 3];
        const int tt = pT[5 * i + 4];
        const float b1x = scc[3*aj+0] - scc[3*ai+0];
        const float b1y = scc[3*aj+1] - scc[3*ai+1];
        const float b1z = scc[3*aj+2] - scc[3*ai+2];
        const float b2x = scc[3*ak+0] - scc[3*aj+0];
        const float b2y = scc[3*ak+1] - scc[3*aj+1];
        const float b2z = scc[3*ak+2] - scc[3*aj+2];
        const float b3x = scc[3*al+0] - scc[3*ak+0];
        const float b3y = scc[3*al+1] - scc[3*ak+1];
        const float b3z = scc[3*al+2] - scc[3*ak+2];
        const float n1x = b1y*b2z - b1z*b2y;
        const float n1y = b1z*b2x - b1x*b2z;
        const float n1z = b1x*b2y - b1y*b2x;
        const float n2x = b2y*b3z - b2z*b3y;
        const float n2y = b2z*b3x - b2x*b3z;
        const float n2z = b2x*b3y - b2y*b3x;
        const float inv = 1.0f / sqrtf(b2x*b2x + b2y*b2y + b2z*b2z + EPSV);
        const float bnx = b2x * inv, bny = b2y * inv, bnz = b2z * inv;
        const float m1x = n1y*bnz - n1z*bny;
        const float m1y = n1z*bnx - n1x*bnz;
        const float m1z = n1x*bny - n1y*bnx;
        const float phi = atan2f(m1x*n2x + m1y*n2y + m1z*n2z,
                                 n1x*n2x + n1y*n2y + n1z*n2z);
        eT += stt[tt * 2 + 0] * (1.0f + cosf(smu[tt] * phi - stt[tt * 2 + 1]));
    }

    // ======== Reduction + plain stores ========
    for (int off = 32; off > 0; off >>= 1) {
        eB += __shfl_down(eB, off);
        eG += __shfl_down(eG, off);
        eT += __shfl_down(eT, off);
    }
    if (l == 0) {
        srd[w * 3 + 0] = eB;
        srd[w * 3 + 1] = eG;
        srd[w * 3 + 2] = eT;
    }
    __syncthreads();
    if (tid == 0) {
        float rB = 0.f, rG = 0.f, rT = 0.f;
        for (int i = 0; i < WAVES; ++i) {
            rB += srd[i * 3 + 0];
            rG += srd[i * 3 + 1];
            rT += srd[i * 3 + 2];
        }
        out[s * 3 + 0] = opt_pars[0] * rB;   // bonds
        out[s * 3 + 1] = opt_pars[1] * rG;   // angles
        out[s * 3 + 2] = opt_pars[2] * rT;   // torsions
    }
}

extern "C" void kernel_launch(void* const* d_in, const int* in_sizes, int n_in,
                              void* d_out, int out_size, void* d_ws, size_t ws_size,
                              hipStream_t stream) {
    const float* F            = (const float*)d_in[0];
    // d_in[1] = lengths (constant, unused)
    const float* bond_type    = (const float*)d_in[2];
    const float* angle_type   = (const float*)d_in[3];
    const float* tor_type     = (const float*)d_in[4];
    const int*   multiplicity = (const int*)  d_in[5];
    const float* opt_pars     = (const float*)d_in[6];
    float* out = (float*)d_out;

    // One block per sample: F fetched exactly once; all out elements written
    // exactly once by plain stores -> no memset / atomics / workspace.
    local_energy_v15<<<dim3(BATCH), dim3(THREADS), 0, stream>>>(
        F, bond_type, angle_type, tor_type, multiplicity, opt_pars, out);
}